// Round 3
// baseline (478.580 us; speedup 1.0000x reference)
//
#include <hip/hip_runtime.h>
#include <hip/hip_bf16.h>

#define NN 8192
#define KF 512
#define FF 64
#define GAT_ALPHA 0.2f
#define MSHIFT 20.0f          // safe upper bound on max_j e2[j] (pre-scale)
#define LOG2E 1.44269504f

#define JCH 512               // j-chunk per double-buffer stage
#define NCH (NN / JCH)        // 16 chunks
#define PST 520               // P-tile stride in bf16: 520/2=260 words ≡ 4 (mod 32) -> 2-way (free) A reads

#define EXP2F(x) __builtin_amdgcn_exp2f(x)   // raw v_exp_f32 (2^x); __exp2f collides with glibc macro

typedef __attribute__((ext_vector_type(8))) __bf16 bf16x8;
typedef __attribute__((ext_vector_type(4))) float f32x4;

// ---------------------------------------------------------------------------
// Kernel A: h = x@W (fp32), e1/e2 = (h@a1, h@a2) * log2(e)  [exp2 inner loop],
//           ht = h^T bf16 [64][8192]. 256 blocks x 256 thr, 32 rows/block.
// ---------------------------------------------------------------------------
__global__ __launch_bounds__(256) void gat_linear(
    const float* __restrict__ x, const float* __restrict__ W,
    const float* __restrict__ av, __hip_bfloat16* __restrict__ ht,
    float* __restrict__ e1, float* __restrict__ e2)
{
    __shared__ float xs[32][33];      // [k][row], stride 33 -> conflict-free staging
    __shared__ float Ws[32][64];      // [k][f]
    __shared__ float ep[2][32][17];   // e1/e2 partials

    const int t  = threadIdx.x;
    const int fq = t & 15;            // f = fq*4 + v
    const int rq = t >> 4;            // rows rq*2 + u (u<2)
    const int i0 = blockIdx.x * 32;

    const int kl = t & 31, r0 = t >> 5;   // xs staging role
    const int fw = t & 63, kq = t >> 6;   // Ws staging role

    float acc[2][4] = {};

    for (int kt = 0; kt < KF; kt += 32) {
        #pragma unroll
        for (int m = 0; m < 4; ++m)
            xs[kl][r0 + 8 * m] = x[(size_t)(i0 + r0 + 8 * m) * KF + kt + kl];
        #pragma unroll
        for (int m = 0; m < 8; ++m)
            Ws[kq + 4 * m][fw] = W[(size_t)(kt + kq + 4 * m) * FF + fw];
        __syncthreads();
        #pragma unroll
        for (int kk = 0; kk < 32; ++kk) {
            float x0 = xs[kk][rq * 2];
            float x1 = xs[kk][rq * 2 + 1];
            f32x4 wv = *(const f32x4*)&Ws[kk][fq * 4];
            #pragma unroll
            for (int v = 0; v < 4; ++v) {
                acc[0][v] += x0 * wv[v];
                acc[1][v] += x1 * wv[v];
            }
        }
        __syncthreads();
    }

    // ht (bf16, transposed): 2 consecutive rows per feature -> 4B stores
    #pragma unroll
    for (int v = 0; v < 4; ++v) {
        int f = fq * 4 + v;
        union { ushort2 q; __hip_bfloat16 h[2]; } pk;
        pk.h[0] = __float2bfloat16(acc[0][v]);
        pk.h[1] = __float2bfloat16(acc[1][v]);
        *(ushort2*)&ht[(size_t)f * NN + i0 + rq * 2] = pk.q;
    }

    // e1/e2 partials (fp32), pre-scaled by log2(e)
    f32x4 a1v = *(const f32x4*)&av[fq * 4];
    f32x4 a2v = *(const f32x4*)&av[64 + fq * 4];
    #pragma unroll
    for (int u = 0; u < 2; ++u) {
        float s1 = 0.f, s2 = 0.f;
        #pragma unroll
        for (int v = 0; v < 4; ++v) {
            s1 += acc[u][v] * a1v[v];
            s2 += acc[u][v] * a2v[v];
        }
        ep[0][rq * 2 + u][fq] = s1;
        ep[1][rq * 2 + u][fq] = s2;
    }
    __syncthreads();
    if (t < 32) {
        float s1 = 0.f, s2 = 0.f;
        #pragma unroll
        for (int q = 0; q < 16; ++q) { s1 += ep[0][t][q]; s2 += ep[1][t][q]; }
        e1[i0 + t] = s1 * LOG2E;
        e2[i0 + t] = s2 * LOG2E;
    }
}

// ---------------------------------------------------------------------------
// Kernel B: masked softmax + attention@h, chunked double-buffered.
// 512 blocks x 256 thr (4 waves); block = 16 rows. Per chunk (J=512):
//   produce P(c) into LDS buf c&1 from adj regs loaded last iteration,
//   issue adj loads for c+1, ONE barrier, 16 MFMAs consuming buf c&1.
// Loads stay in flight across the barrier + MFMA region -> HBM-bound.
// ---------------------------------------------------------------------------
__global__ __launch_bounds__(256, 2) void gat_attn(
    const int* __restrict__ adj, const __hip_bfloat16* __restrict__ ht,
    const float* __restrict__ e1, const float* __restrict__ e2,
    float* __restrict__ out)
{
    __shared__ __hip_bfloat16 ps[2][16][PST];
    __shared__ float l_red[16];

    const int t    = threadIdx.x;
    const int ii   = t >> 4;        // stage-1 row 0..15
    const int jq   = t & 15;        // stage-1 j group (4 j's)
    const int i0   = blockIdx.x * 16;
    const int lane = t & 63;
    const int wv   = t >> 6;        // wave id = feature slice
    const int n16  = lane & 15;
    const int quad = lane >> 4;

    const float e1L = e1[i0 + ii];                 // already *log2e
    float ms = e1L + MSHIFT * LOG2E;
    const float miL = ms > 0.f ? ms : GAT_ALPHA * ms;

    if (t < 16) l_red[t] = 0.f;

    const int*   arow = adj + (size_t)(i0 + ii) * NN + jq * 4;
    const float* e2p  = e2 + jq * 4;
    const __hip_bfloat16* hbase = ht + (size_t)(wv * 16 + n16) * NN + quad * 8;

    // prologue: adj loads for chunk 0 (8 int4 per thread, kept in regs)
    int4 aj[8];
    #pragma unroll
    for (int g = 0; g < 8; ++g)
        aj[g] = *(const int4*)(arow + g * 64);

    float lpart = 0.f;
    f32x4 dacc = {0.f, 0.f, 0.f, 0.f};

    for (int c = 0; c < NCH; ++c) {
        const int buf = c & 1;
        // ---- produce P(c) from regs ----
        #pragma unroll
        for (int g = 0; g < 8; ++g) {
            float4 e_ = *(const float4*)(e2p + c * JCH + g * 64);   // L1/L2 hot
            int4   a_ = aj[g];
            union { uint2 u; __hip_bfloat16 h[4]; } pk;
            float s_, p_;
            s_ = e1L + e_.x; s_ = s_ > 0.f ? s_ : GAT_ALPHA * s_;
            p_ = a_.x > 0 ? EXP2F(s_ - miL) : 0.f;
            pk.h[0] = __float2bfloat16(p_); lpart += __bfloat162float(pk.h[0]);
            s_ = e1L + e_.y; s_ = s_ > 0.f ? s_ : GAT_ALPHA * s_;
            p_ = a_.y > 0 ? EXP2F(s_ - miL) : 0.f;
            pk.h[1] = __float2bfloat16(p_); lpart += __bfloat162float(pk.h[1]);
            s_ = e1L + e_.z; s_ = s_ > 0.f ? s_ : GAT_ALPHA * s_;
            p_ = a_.z > 0 ? EXP2F(s_ - miL) : 0.f;
            pk.h[2] = __float2bfloat16(p_); lpart += __bfloat162float(pk.h[2]);
            s_ = e1L + e_.w; s_ = s_ > 0.f ? s_ : GAT_ALPHA * s_;
            p_ = a_.w > 0 ? EXP2F(s_ - miL) : 0.f;
            pk.h[3] = __float2bfloat16(p_); lpart += __bfloat162float(pk.h[3]);
            *(uint2*)&ps[buf][ii][g * 64 + jq * 4] = pk.u;
        }
        // ---- issue adj loads for chunk c+1 (in flight across barrier+MFMA) ----
        if (c + 1 < NCH) {
            #pragma unroll
            for (int g = 0; g < 8; ++g)
                aj[g] = *(const int4*)(arow + (c + 1) * JCH + g * 64);
        }
        __syncthreads();
        // ---- consume P(c): 16 x mfma_16x16x32 (A = P from LDS, B = hT from L2) ----
        const __hip_bfloat16* hb = hbase + (size_t)c * JCH;
        #pragma unroll
        for (int kk = 0; kk < JCH / 32; ++kk) {
            bf16x8 af = *(const bf16x8*)&ps[buf][n16][kk * 32 + quad * 8];
            bf16x8 bf = *(const bf16x8*)(hb + kk * 32);
            dacc = __builtin_amdgcn_mfma_f32_16x16x32_bf16(af, bf, dacc, 0, 0, 0);
        }
        // no trailing barrier: next iter writes buf^1; buf reuse is fenced by
        // the next iteration's barrier.
    }

    atomicAdd(&l_red[ii], lpart);
    __syncthreads();

    // epilogue: D layout col=lane&15, row=quad*4+reg (m89-verified)
    #pragma unroll
    for (int r = 0; r < 4; ++r) {
        int row = quad * 4 + r;
        float hv = dacc[r] / l_red[row];
        float o = hv > 0.f ? hv : __expf(hv) - 1.f;  // elu
        out[(size_t)(i0 + row) * FF + wv * 16 + n16] = o;
    }
}

extern "C" void kernel_launch(void* const* d_in, const int* in_sizes, int n_in,
                              void* d_out, int out_size, void* d_ws, size_t ws_size,
                              hipStream_t stream) {
    const float* x   = (const float*)d_in[0];
    const int*   adj = (const int*)d_in[1];
    const float* W   = (const float*)d_in[2];
    const float* av  = (const float*)d_in[3];
    float* out = (float*)d_out;

    // ws layout: ht bf16 [64][8192] (1 MB) | e1 f32[8192] | e2 f32[8192]
    char* wsb = (char*)d_ws;
    __hip_bfloat16* ht = (__hip_bfloat16*)wsb;
    float* e1 = (float*)(wsb + (1 << 20));
    float* e2 = e1 + NN;

    gat_linear<<<256, 256, 0, stream>>>(x, W, av, ht, e1, e2);
    gat_attn<<<512, 256, 0, stream>>>(adj, ht, e1, e2, out);
}

// Round 4
// 429.993 us; speedup vs baseline: 1.1130x; 1.1130x over previous
//
#include <hip/hip_runtime.h>
#include <hip/hip_bf16.h>

#define NN 8192
#define KF 512
#define FF 64
#define GAT_ALPHA 0.2f
#define MSHIFT 20.0f          // safe upper bound on max_j e2[j] (pre-scale)
#define LOG2E 1.44269504f

#define JSPLIT 4              // j-range split across blocks (occupancy: 2048 blocks = 8/CU)
#define JCH 512               // j-chunk per LDS stage
#define NCHB (NN / JSPLIT / JCH)   // 4 chunks per block
#define PST 520               // P stride bf16: 260 words ≡ 4 (mod 32) -> 2-way (free)

#define EXP2F(x) __builtin_amdgcn_exp2f(x)

typedef __attribute__((ext_vector_type(8))) __bf16 bf16x8;
typedef __attribute__((ext_vector_type(4))) float f32x4;

// ---------------------------------------------------------------------------
// zero acc[8192*64] + lsum[8192] (contiguous, 532480 floats = 133120 float4)
// ---------------------------------------------------------------------------
__global__ __launch_bounds__(256) void zero_ws(float4* __restrict__ p) {
    p[blockIdx.x * 256 + threadIdx.x] = make_float4(0.f, 0.f, 0.f, 0.f);
}

// ---------------------------------------------------------------------------
// Kernel A: h = x@W (fp32), e1/e2 = (h@a1, h@a2) * log2(e),
//           ht = h^T bf16 [64][8192]. 256 blocks x 256 thr, 32 rows/block.
// ---------------------------------------------------------------------------
__global__ __launch_bounds__(256) void gat_linear(
    const float* __restrict__ x, const float* __restrict__ W,
    const float* __restrict__ av, __hip_bfloat16* __restrict__ ht,
    float* __restrict__ e1, float* __restrict__ e2)
{
    __shared__ float xs[32][33];
    __shared__ float Ws[32][64];
    __shared__ float ep[2][32][17];

    const int t  = threadIdx.x;
    const int fq = t & 15;
    const int rq = t >> 4;
    const int i0 = blockIdx.x * 32;

    const int kl = t & 31, r0 = t >> 5;
    const int fw = t & 63, kq = t >> 6;

    float acc[2][4] = {};

    for (int kt = 0; kt < KF; kt += 32) {
        #pragma unroll
        for (int m = 0; m < 4; ++m)
            xs[kl][r0 + 8 * m] = x[(size_t)(i0 + r0 + 8 * m) * KF + kt + kl];
        #pragma unroll
        for (int m = 0; m < 8; ++m)
            Ws[kq + 4 * m][fw] = W[(size_t)(kt + kq + 4 * m) * FF + fw];
        __syncthreads();
        #pragma unroll
        for (int kk = 0; kk < 32; ++kk) {
            float x0 = xs[kk][rq * 2];
            float x1 = xs[kk][rq * 2 + 1];
            f32x4 wv = *(const f32x4*)&Ws[kk][fq * 4];
            #pragma unroll
            for (int v = 0; v < 4; ++v) {
                acc[0][v] += x0 * wv[v];
                acc[1][v] += x1 * wv[v];
            }
        }
        __syncthreads();
    }

    #pragma unroll
    for (int v = 0; v < 4; ++v) {
        int f = fq * 4 + v;
        union { ushort2 q; __hip_bfloat16 h[2]; } pk;
        pk.h[0] = __float2bfloat16(acc[0][v]);
        pk.h[1] = __float2bfloat16(acc[1][v]);
        *(ushort2*)&ht[(size_t)f * NN + i0 + rq * 2] = pk.q;
    }

    f32x4 a1v = *(const f32x4*)&av[fq * 4];
    f32x4 a2v = *(const f32x4*)&av[64 + fq * 4];
    #pragma unroll
    for (int u = 0; u < 2; ++u) {
        float s1 = 0.f, s2 = 0.f;
        #pragma unroll
        for (int v = 0; v < 4; ++v) {
            s1 += acc[u][v] * a1v[v];
            s2 += acc[u][v] * a2v[v];
        }
        ep[0][rq * 2 + u][fq] = s1;
        ep[1][rq * 2 + u][fq] = s2;
    }
    __syncthreads();
    if (t < 32) {
        float s1 = 0.f, s2 = 0.f;
        #pragma unroll
        for (int q = 0; q < 16; ++q) { s1 += ep[0][t][q]; s2 += ep[1][t][q]; }
        e1[i0 + t] = s1 * LOG2E;
        e2[i0 + t] = s2 * LOG2E;
    }
}

// ---------------------------------------------------------------------------
// Kernel B: masked softmax + P@h partials. Grid 2048 = 512 row-groups x 4
// j-quarters -> 8 blocks/CU (latency-bound fix). Single LDS P buffer
// (16.7 KB), 2 barriers per 512-j chunk, adj prefetch in regs stays in
// flight across the MFMA phase. Partials -> global fp32 atomics.
// ---------------------------------------------------------------------------
__global__ __launch_bounds__(256, 8) void gat_attn(
    const int* __restrict__ adj, const __hip_bfloat16* __restrict__ ht,
    const float* __restrict__ e1, const float* __restrict__ e2,
    float* __restrict__ acc, float* __restrict__ lsum)
{
    __shared__ __hip_bfloat16 ps[16][PST];
    __shared__ float l_red[16];

    const int t     = threadIdx.x;
    const int ii    = t >> 4;
    const int jq    = t & 15;
    const int i0    = (blockIdx.x >> 2) * 16;
    const int jbase = (blockIdx.x & 3) * (NN / JSPLIT);
    const int lane  = t & 63;
    const int wv    = t >> 6;
    const int n16   = lane & 15;
    const int quad  = lane >> 4;

    const float e1L = e1[i0 + ii];
    float ms = e1L + MSHIFT * LOG2E;
    const float miL = ms > 0.f ? ms : GAT_ALPHA * ms;

    if (t < 16) l_red[t] = 0.f;

    const int*   arow = adj + (size_t)(i0 + ii) * NN + jbase + jq * 4;
    const float* e2p  = e2 + jbase + jq * 4;
    const __hip_bfloat16* hbase = ht + (size_t)(wv * 16 + n16) * NN + jbase + quad * 8;

    // prologue: adj loads for chunk 0
    int4 aj[8];
    #pragma unroll
    for (int g = 0; g < 8; ++g)
        aj[g] = *(const int4*)(arow + g * 64);

    float lpart = 0.f;
    f32x4 dacc = {0.f, 0.f, 0.f, 0.f};

    for (int c = 0; c < NCHB; ++c) {
        // ---- produce P(c) from regs ----
        #pragma unroll
        for (int g = 0; g < 8; ++g) {
            float4 e_ = *(const float4*)(e2p + c * JCH + g * 64);
            int4   a_ = aj[g];
            union { uint2 u; __hip_bfloat16 h[4]; } pk;
            float s_, p_;
            s_ = e1L + e_.x; s_ = s_ > 0.f ? s_ : GAT_ALPHA * s_;
            p_ = a_.x > 0 ? EXP2F(s_ - miL) : 0.f;
            pk.h[0] = __float2bfloat16(p_); lpart += __bfloat162float(pk.h[0]);
            s_ = e1L + e_.y; s_ = s_ > 0.f ? s_ : GAT_ALPHA * s_;
            p_ = a_.y > 0 ? EXP2F(s_ - miL) : 0.f;
            pk.h[1] = __float2bfloat16(p_); lpart += __bfloat162float(pk.h[1]);
            s_ = e1L + e_.z; s_ = s_ > 0.f ? s_ : GAT_ALPHA * s_;
            p_ = a_.z > 0 ? EXP2F(s_ - miL) : 0.f;
            pk.h[2] = __float2bfloat16(p_); lpart += __bfloat162float(pk.h[2]);
            s_ = e1L + e_.w; s_ = s_ > 0.f ? s_ : GAT_ALPHA * s_;
            p_ = a_.w > 0 ? EXP2F(s_ - miL) : 0.f;
            pk.h[3] = __float2bfloat16(p_); lpart += __bfloat162float(pk.h[3]);
            *(uint2*)&ps[ii][g * 64 + jq * 4] = pk.u;
        }
        // ---- prefetch adj for chunk c+1 (in flight across barrier + MFMA) ----
        if (c + 1 < NCHB) {
            #pragma unroll
            for (int g = 0; g < 8; ++g)
                aj[g] = *(const int4*)(arow + (c + 1) * JCH + g * 64);
        }
        __syncthreads();
        // ---- consume P(c): 16 x mfma_16x16x32 (A = P in LDS, B = hT via L2) ----
        const __hip_bfloat16* hb = hbase + (size_t)c * JCH;
        #pragma unroll
        for (int kk = 0; kk < JCH / 32; ++kk) {
            bf16x8 af = *(const bf16x8*)&ps[n16][kk * 32 + quad * 8];
            bf16x8 bf = *(const bf16x8*)(hb + kk * 32);
            dacc = __builtin_amdgcn_mfma_f32_16x16x32_bf16(af, bf, dacc, 0, 0, 0);
        }
        __syncthreads();
    }

    atomicAdd(&l_red[ii], lpart);
    __syncthreads();
    if (t < 16) atomicAdd(&lsum[i0 + t], l_red[t]);

    // D layout col=lane&15, row=quad*4+reg (m89-verified)
    #pragma unroll
    for (int r = 0; r < 4; ++r) {
        int row = quad * 4 + r;
        atomicAdd(&acc[(size_t)(i0 + row) * FF + wv * 16 + n16], dacc[r]);
    }
}

// ---------------------------------------------------------------------------
// Epilogue: out = elu(acc / lsum)
// ---------------------------------------------------------------------------
__global__ __launch_bounds__(256) void gat_epilogue(
    const float* __restrict__ acc, const float* __restrict__ lsum,
    float* __restrict__ out)
{
    int idx = (blockIdx.x * 256 + threadIdx.x) * 4;   // 4 consecutive, same row
    float li = 1.f / lsum[idx >> 6];
    f32x4 a = *(const f32x4*)(acc + idx);
    f32x4 o;
    #pragma unroll
    for (int v = 0; v < 4; ++v) {
        float hv = a[v] * li;
        o[v] = hv > 0.f ? hv : __expf(hv) - 1.f;
    }
    *(f32x4*)(out + idx) = o;
}

extern "C" void kernel_launch(void* const* d_in, const int* in_sizes, int n_in,
                              void* d_out, int out_size, void* d_ws, size_t ws_size,
                              hipStream_t stream) {
    const float* x   = (const float*)d_in[0];
    const int*   adj = (const int*)d_in[1];
    const float* W   = (const float*)d_in[2];
    const float* av  = (const float*)d_in[3];
    float* out = (float*)d_out;

    // ws: ht bf16[64*8192] (1MB) | e1 f32[8192] | e2 f32[8192] | acc f32[8192*64] | lsum f32[8192]
    char* wsb = (char*)d_ws;
    __hip_bfloat16* ht = (__hip_bfloat16*)wsb;
    float* e1  = (float*)(wsb + (1 << 20));
    float* e2  = e1 + NN;
    float* acc = e2 + NN;
    float* lsum = acc + (size_t)NN * FF;

    zero_ws<<<(NN * FF + NN) / 1024, 256, 0, stream>>>((float4*)acc);
    gat_linear<<<256, 256, 0, stream>>>(x, W, av, ht, e1, e2);
    gat_attn<<<NN / 16 * JSPLIT, 256, 0, stream>>>(adj, ht, e1, e2, acc, lsum);
    gat_epilogue<<<NN * FF / 1024, 256, 0, stream>>>(acc, lsum, out);
}

// Round 5
// 427.539 us; speedup vs baseline: 1.1194x; 1.0057x over previous
//
#include <hip/hip_runtime.h>
#include <hip/hip_bf16.h>

#define NN 8192
#define KF 512
#define FF 64
#define GAT_ALPHA 0.2f
#define MSHIFT 20.0f          // safe upper bound on max_j e2[j] (pre-scale)
#define LOG2E 1.44269504f

#define JSPLIT 16             // j-range split; grid = 128 row-groups x 16
#define JW (NN / JSPLIT)      // 512 j's per wave
#define KSTEPS (JW / 32)      // 16 k-steps of 32

#define EXP2F(x) __builtin_amdgcn_exp2f(x)

typedef __attribute__((ext_vector_type(8))) __bf16 bf16x8;
typedef __attribute__((ext_vector_type(4))) float f32x4;

// ---------------------------------------------------------------------------
// Kernel A: h = x@W (fp32), e1/e2 = (h@a1, h@a2) * log2(e),
//           ht = h^T bf16 [64][8192]. 256 blocks x 256 thr, 32 rows/block.
// ---------------------------------------------------------------------------
__global__ __launch_bounds__(256) void gat_linear(
    const float* __restrict__ x, const float* __restrict__ W,
    const float* __restrict__ av, __hip_bfloat16* __restrict__ ht,
    float* __restrict__ e1, float* __restrict__ e2)
{
    __shared__ float xs[32][33];
    __shared__ float Ws[32][64];
    __shared__ float ep[2][32][17];

    const int t  = threadIdx.x;
    const int fq = t & 15;
    const int rq = t >> 4;
    const int i0 = blockIdx.x * 32;

    const int kl = t & 31, r0 = t >> 5;
    const int fw = t & 63, kq = t >> 6;

    float acc[2][4] = {};

    for (int kt = 0; kt < KF; kt += 32) {
        #pragma unroll
        for (int m = 0; m < 4; ++m)
            xs[kl][r0 + 8 * m] = x[(size_t)(i0 + r0 + 8 * m) * KF + kt + kl];
        #pragma unroll
        for (int m = 0; m < 8; ++m)
            Ws[kq + 4 * m][fw] = W[(size_t)(kt + kq + 4 * m) * FF + fw];
        __syncthreads();
        #pragma unroll
        for (int kk = 0; kk < 32; ++kk) {
            float x0 = xs[kk][rq * 2];
            float x1 = xs[kk][rq * 2 + 1];
            f32x4 wv = *(const f32x4*)&Ws[kk][fq * 4];
            #pragma unroll
            for (int v = 0; v < 4; ++v) {
                acc[0][v] += x0 * wv[v];
                acc[1][v] += x1 * wv[v];
            }
        }
        __syncthreads();
    }

    #pragma unroll
    for (int v = 0; v < 4; ++v) {
        int f = fq * 4 + v;
        union { ushort2 q; __hip_bfloat16 h[2]; } pk;
        pk.h[0] = __float2bfloat16(acc[0][v]);
        pk.h[1] = __float2bfloat16(acc[1][v]);
        *(ushort2*)&ht[(size_t)f * NN + i0 + rq * 2] = pk.q;
    }

    f32x4 a1v = *(const f32x4*)&av[fq * 4];
    f32x4 a2v = *(const f32x4*)&av[64 + fq * 4];
    #pragma unroll
    for (int u = 0; u < 2; ++u) {
        float s1 = 0.f, s2 = 0.f;
        #pragma unroll
        for (int v = 0; v < 4; ++v) {
            s1 += acc[u][v] * a1v[v];
            s2 += acc[u][v] * a2v[v];
        }
        ep[0][rq * 2 + u][fq] = s1;
        ep[1][rq * 2 + u][fq] = s2;
    }
    __syncthreads();
    if (t < 32) {
        float s1 = 0.f, s2 = 0.f;
        #pragma unroll
        for (int q = 0; q < 16; ++q) { s1 += ep[0][t][q]; s2 += ep[1][t][q]; }
        e1[i0 + t] = s1 * LOG2E;
        e2[i0 + t] = s2 * LOG2E;
    }
}

// ---------------------------------------------------------------------------
// Kernel B: barrier-free. Each wave owns 16 rows x 512 j's; produces P
// directly in MFMA A-fragment registers (A[m=lane&15][k=quad*8+jj]) and does
// 4 MFMAs/k-step (all 64 features). Register ping-pong double-buffer; the
// compiler emits fine-grained vmcnt (no s_barrier => no vmcnt(0) drains).
// Partials (dacc, l) written once per j-split slice — no atomics.
// ---------------------------------------------------------------------------
__global__ __launch_bounds__(256, 4) void gat_attn(
    const int* __restrict__ adj, const __hip_bfloat16* __restrict__ ht,
    const float* __restrict__ e1, const float* __restrict__ e2,
    float* __restrict__ accs, float* __restrict__ lsums)
{
    const int t     = threadIdx.x;
    const int lane  = t & 63;
    const int wv    = t >> 6;
    const int n16   = lane & 15;
    const int quad  = lane >> 4;
    const int split = blockIdx.x & (JSPLIT - 1);
    const int i0    = (blockIdx.x >> 4) * 64 + wv * 16;
    const int j0    = split * JW;
    const int row   = i0 + n16;

    const float e1L = e1[row];
    float ms = e1L + MSHIFT * LOG2E;
    const float miL = ms > 0.f ? ms : GAT_ALPHA * ms;

    const int*            ap  = adj + (size_t)row * NN + j0 + quad * 8;
    const float*          epx = e2 + j0 + quad * 8;
    const __hip_bfloat16* hp  = ht + (size_t)n16 * NN + j0 + quad * 8;

    int4   aA[2][2];
    float4 eA[2][2];
    bf16x8 bA[2][4];
    float lpart = 0.f;
    f32x4 dacc[4] = {{0.f,0.f,0.f,0.f},{0.f,0.f,0.f,0.f},{0.f,0.f,0.f,0.f},{0.f,0.f,0.f,0.f}};

#define LOADB(sl, st)                                                         \
    {                                                                         \
        aA[sl][0] = *(const int4*)(ap + (st) * 32);                           \
        aA[sl][1] = *(const int4*)(ap + (st) * 32 + 4);                       \
        eA[sl][0] = *(const float4*)(epx + (st) * 32);                        \
        eA[sl][1] = *(const float4*)(epx + (st) * 32 + 4);                    \
        bA[sl][0] = *(const bf16x8*)(hp + (size_t)(st) * 32);                 \
        bA[sl][1] = *(const bf16x8*)(hp + (size_t)16 * NN + (st) * 32);       \
        bA[sl][2] = *(const bf16x8*)(hp + (size_t)32 * NN + (st) * 32);       \
        bA[sl][3] = *(const bf16x8*)(hp + (size_t)48 * NN + (st) * 32);       \
    }

    LOADB(0, 0)
    LOADB(1, 1)

    #pragma unroll
    for (int st = 0; st < KSTEPS; ++st) {
        const int sl = st & 1;
        union { bf16x8 v; __hip_bfloat16 h[8]; } af;
        const int*   av4 = (const int*)&aA[sl][0];
        const float* ev4 = (const float*)&eA[sl][0];
        #pragma unroll
        for (int jj = 0; jj < 8; ++jj) {
            float s_ = e1L + ev4[jj];
            s_ = s_ > 0.f ? s_ : GAT_ALPHA * s_;
            float p_ = av4[jj] > 0 ? EXP2F(s_ - miL) : 0.f;
            af.h[jj] = __float2bfloat16(p_);
            lpart += __bfloat162float(af.h[jj]);
        }
        bf16x8 b0 = bA[sl][0], b1 = bA[sl][1], b2 = bA[sl][2], b3 = bA[sl][3];
        if (st + 2 < KSTEPS) LOADB(sl, st + 2)
        dacc[0] = __builtin_amdgcn_mfma_f32_16x16x32_bf16(af.v, b0, dacc[0], 0, 0, 0);
        dacc[1] = __builtin_amdgcn_mfma_f32_16x16x32_bf16(af.v, b1, dacc[1], 0, 0, 0);
        dacc[2] = __builtin_amdgcn_mfma_f32_16x16x32_bf16(af.v, b2, dacc[2], 0, 0, 0);
        dacc[3] = __builtin_amdgcn_mfma_f32_16x16x32_bf16(af.v, b3, dacc[3], 0, 0, 0);
    }
#undef LOADB

    // row-sum of p across the 4 quads (lanes n16, n16+16, n16+32, n16+48)
    lpart += __shfl_xor(lpart, 16);
    lpart += __shfl_xor(lpart, 32);
    if (quad == 0) lsums[(size_t)split * NN + row] = lpart;

    // D layout: col = lane&15 (feature-within-tile), row = quad*4 + reg
    float* ab = accs + (size_t)split * NN * FF;
    #pragma unroll
    for (int ft = 0; ft < 4; ++ft)
        #pragma unroll
        for (int r = 0; r < 4; ++r)
            ab[(size_t)(i0 + quad * 4 + r) * FF + ft * 16 + n16] = dacc[ft][r];
}

// ---------------------------------------------------------------------------
// Epilogue: out = elu( (sum_s accs[s]) / (sum_s lsums[s]) )
// ---------------------------------------------------------------------------
__global__ __launch_bounds__(256) void gat_epilogue(
    const float* __restrict__ accs, const float* __restrict__ lsums,
    float* __restrict__ out)
{
    const int idx = (blockIdx.x * 256 + threadIdx.x) * 4;  // 4 consecutive f, same row
    const int row = idx >> 6;

    float l = 0.f;
    #pragma unroll
    for (int s = 0; s < JSPLIT; ++s) l += lsums[(size_t)s * NN + row];

    f32x4 a = {0.f, 0.f, 0.f, 0.f};
    #pragma unroll
    for (int s = 0; s < JSPLIT; ++s) {
        f32x4 v = *(const f32x4*)(accs + (size_t)s * NN * FF + idx);
        a.x += v.x; a.y += v.y; a.z += v.z; a.w += v.w;
    }

    const float li = 1.f / l;
    f32x4 o;
    #pragma unroll
    for (int v = 0; v < 4; ++v) {
        float hv = a[v] * li;
        o[v] = hv > 0.f ? hv : __expf(hv) - 1.f;
    }
    *(f32x4*)(out + idx) = o;
}

extern "C" void kernel_launch(void* const* d_in, const int* in_sizes, int n_in,
                              void* d_out, int out_size, void* d_ws, size_t ws_size,
                              hipStream_t stream) {
    const float* x   = (const float*)d_in[0];
    const int*   adj = (const int*)d_in[1];
    const float* W   = (const float*)d_in[2];
    const float* av  = (const float*)d_in[3];
    float* out = (float*)d_out;

    // ws: ht bf16[64*8192] (1MB) | e1 f32[8192] | e2 f32[8192]
    //     | accs f32[16][8192*64] (32MB) | lsums f32[16][8192] (512KB)
    char* wsb = (char*)d_ws;
    __hip_bfloat16* ht = (__hip_bfloat16*)wsb;
    float* e1    = (float*)(wsb + (1 << 20));
    float* e2    = e1 + NN;
    float* accs  = e2 + NN;
    float* lsums = accs + (size_t)JSPLIT * NN * FF;

    gat_linear<<<256, 256, 0, stream>>>(x, W, av, ht, e1, e2);
    gat_attn<<<(NN / 64) * JSPLIT, 256, 0, stream>>>(adj, ht, e1, e2, accs, lsums);
    gat_epilogue<<<NN * FF / 1024, 256, 0, stream>>>(accs, lsums, out);
}